// Round 1
// baseline (39.323 us; speedup 1.0000x reference)
//
#include <hip/hip_runtime.h>

// Problem: N=8, L=2048, E=1024, V=512. Only row l=L-1 of the attention output
// feeds the final logits, so everything reduces to per-batch GEMV-like passes.
#define N_B 8
#define L_S 2048
#define E_D 1024
#define V_D 512
#define CHUNKS 32
#define CHUNK_M (L_S / CHUNKS) // 64

__device__ inline float wave_reduce_sum(float v) {
    #pragma unroll
    for (int off = 32; off > 0; off >>= 1)
        v += __shfl_down(v, off, 64);
    return v;
}

// q_row[n,f] = Wa_b[f] + sum_e tokens[n,L-1,e] * Wa_w[f,e]
// one wave per (n,f); 8192 waves
__global__ void k_qrow(const int* __restrict__ tokens, const float* __restrict__ Wa_w,
                       const float* __restrict__ Wa_b, float* __restrict__ q_row) {
    int wid  = blockIdx.x * (blockDim.x >> 6) + (threadIdx.x >> 6);
    int lane = threadIdx.x & 63;
    int n = wid >> 10;            // /E_D
    int f = wid & (E_D - 1);
    const int*   xrow = tokens + ((size_t)n * L_S + (L_S - 1)) * E_D;
    const float* wrow = Wa_w + (size_t)f * E_D;
    float acc = 0.f;
    #pragma unroll
    for (int k = 0; k < E_D; k += 256) {
        int idx = k + lane * 4;
        int4   t = *reinterpret_cast<const int4*>(xrow + idx);
        float4 w = *reinterpret_cast<const float4*>(wrow + idx);
        acc += (float)t.x * w.x + (float)t.y * w.y + (float)t.z * w.z + (float)t.w * w.w;
    }
    acc = wave_reduce_sum(acc);
    if (lane == 0) q_row[wid] = acc + Wa_b[f];
}

// scores[n,m] = sum_f q_row[n,f] * tokens[n,m,f]   (dominant pass #1: reads all tokens)
// one wave per (n,m); 16384 waves
__global__ void k_scores(const int* __restrict__ tokens, const float* __restrict__ q_row,
                         float* __restrict__ scores) {
    int wid  = blockIdx.x * (blockDim.x >> 6) + (threadIdx.x >> 6);
    int lane = threadIdx.x & 63;
    int n = wid >> 11;            // /L_S
    int m = wid & (L_S - 1);
    const int*   xrow = tokens + ((size_t)n * L_S + m) * E_D;
    const float* q    = q_row + n * E_D;
    float acc = 0.f;
    #pragma unroll
    for (int k = 0; k < E_D; k += 256) {
        int idx = k + lane * 4;
        int4   t  = *reinterpret_cast<const int4*>(xrow + idx);
        float4 qq = *reinterpret_cast<const float4*>(q + idx);
        acc += (float)t.x * qq.x + (float)t.y * qq.y + (float)t.z * qq.z + (float)t.w * qq.w;
    }
    acc = wave_reduce_sum(acc);
    if (lane == 0) scores[wid] = acc;
}

// softmax over m per n; one block (256 threads) per n
__global__ void k_softmax(const float* __restrict__ scores, float* __restrict__ wts) {
    int n = blockIdx.x;
    int t = threadIdx.x;
    const float* s = scores + n * L_S;
    float*       w = wts    + n * L_S;
    __shared__ float red[256];
    float v[8];
    float lmax = -1e30f;
    #pragma unroll
    for (int i = 0; i < 8; ++i) { v[i] = s[t + i * 256]; lmax = fmaxf(lmax, v[i]); }
    red[t] = lmax; __syncthreads();
    for (int off = 128; off > 0; off >>= 1) {
        if (t < off) red[t] = fmaxf(red[t], red[t + off]);
        __syncthreads();
    }
    float gmax = red[0]; __syncthreads();
    float lsum = 0.f;
    #pragma unroll
    for (int i = 0; i < 8; ++i) { v[i] = expf(v[i] - gmax); lsum += v[i]; }
    red[t] = lsum; __syncthreads();
    for (int off = 128; off > 0; off >>= 1) {
        if (t < off) red[t] += red[t + off];
        __syncthreads();
    }
    float inv = 1.f / red[0];
    #pragma unroll
    for (int i = 0; i < 8; ++i) w[t + i * 256] = v[i] * inv;
}

// partial[n,c,e] = sum_{m in chunk c} wts[n,m] * tokens[n,m,e]  (dominant pass #2)
// one block (1024 threads, thread=e) per (n,chunk); 256 blocks
__global__ void k_attn_partial(const int* __restrict__ tokens, const float* __restrict__ wts,
                               float* __restrict__ partial) {
    int n = blockIdx.x / CHUNKS;
    int c = blockIdx.x % CHUNKS;
    int e = threadIdx.x;
    const int*   base = tokens + ((size_t)n * L_S + (size_t)c * CHUNK_M) * E_D;
    const float* w    = wts + n * L_S + c * CHUNK_M;
    float acc = 0.f;
    #pragma unroll 4
    for (int m = 0; m < CHUNK_M; ++m) {
        acc += w[m] * (float)base[(size_t)m * E_D + e];
    }
    partial[(size_t)blockIdx.x * E_D + e] = acc;
}

// a_row[n,e] = sum_c partial[n,c,e]
__global__ void k_reduce_a(const float* __restrict__ partial, float* __restrict__ a_row) {
    int i = blockIdx.x * blockDim.x + threadIdx.x; // n*E + e
    int n = i >> 10;
    int e = i & (E_D - 1);
    float acc = 0.f;
    #pragma unroll
    for (int c = 0; c < CHUNKS; ++c)
        acc += partial[((size_t)(n * CHUNKS + c)) * E_D + e];
    a_row[i] = acc;
}

// out[n,v] = Wb_b[v] + sum_e a_row[n,e] * Wb_w[v,e]
// one wave per (n,v); 4096 waves
__global__ void k_out(const float* __restrict__ a_row, const float* __restrict__ Wb_w,
                      const float* __restrict__ Wb_b, float* __restrict__ out) {
    int wid  = blockIdx.x * (blockDim.x >> 6) + (threadIdx.x >> 6);
    int lane = threadIdx.x & 63;
    int n = wid >> 9;             // /V_D
    int v = wid & (V_D - 1);
    const float* a  = a_row + n * E_D;
    const float* wr = Wb_w + (size_t)v * E_D;
    float acc = 0.f;
    #pragma unroll
    for (int k = 0; k < E_D; k += 256) {
        int idx = k + lane * 4;
        float4 av = *reinterpret_cast<const float4*>(a + idx);
        float4 wv = *reinterpret_cast<const float4*>(wr + idx);
        acc += av.x * wv.x + av.y * wv.y + av.z * wv.z + av.w * wv.w;
    }
    acc = wave_reduce_sum(acc);
    if (lane == 0) out[wid] = acc + Wb_b[v];
}

extern "C" void kernel_launch(void* const* d_in, const int* in_sizes, int n_in,
                              void* d_out, int out_size, void* d_ws, size_t ws_size,
                              hipStream_t stream) {
    const int*   tokens = (const int*)  d_in[0];
    const float* Wa_w   = (const float*)d_in[1];
    const float* Wa_b   = (const float*)d_in[2];
    const float* Wb_w   = (const float*)d_in[3];
    const float* Wb_b   = (const float*)d_in[4];
    float* out = (float*)d_out;

    float* ws      = (float*)d_ws;
    float* q_row   = ws;                                   // N*E      = 8192
    float* scores  = q_row  + N_B * E_D;                   // N*L      = 16384
    float* wts     = scores + N_B * L_S;                   // N*L      = 16384
    float* partial = wts    + N_B * L_S;                   // N*CH*E   = 262144
    float* a_row   = partial + (size_t)N_B * CHUNKS * E_D; // N*E      = 8192

    // 1) q_row: 8192 waves -> 2048 blocks of 256
    k_qrow<<<dim3((N_B * E_D) / 4), dim3(256), 0, stream>>>(tokens, Wa_w, Wa_b, q_row);
    // 2) scores: 16384 waves -> 4096 blocks of 256
    k_scores<<<dim3((N_B * L_S) / 4), dim3(256), 0, stream>>>(tokens, q_row, scores);
    // 3) softmax: 8 blocks of 256
    k_softmax<<<dim3(N_B), dim3(256), 0, stream>>>(scores, wts);
    // 4) attention-weighted token sum partials: 256 blocks of 1024
    k_attn_partial<<<dim3(N_B * CHUNKS), dim3(1024), 0, stream>>>(tokens, wts, partial);
    // 5) reduce partials: 32 blocks of 256
    k_reduce_a<<<dim3((N_B * E_D) / 256), dim3(256), 0, stream>>>(partial, a_row);
    // 6) final GEMV: 4096 waves -> 1024 blocks of 256
    k_out<<<dim3((N_B * V_D) / 4), dim3(256), 0, stream>>>(a_row, Wb_w, Wb_b, out);
}

// Round 2
// 30.831 us; speedup vs baseline: 1.2755x; 1.2755x over previous
//
#include <hip/hip_runtime.h>

// N=8, L=2048, E=1024, V=512. Only l=L-1 feeds the logits -> GEMV pipeline.
// Key fusion: tokens (64 MB) are read exactly ONCE. Scores + chunk-local
// softmax + weighted token sum happen in one kernel; token bits are packed
// into LDS during the score pass (tokens are {0,1}) so the weighted-sum
// phase never touches global tokens again.
#define NB 8
#define LS 2048
#define ED 1024
#define VD 512
#define CH 32          // chunks over m
#define CM 64          // m per chunk

__device__ inline float wave_reduce_sum(float v) {
    #pragma unroll
    for (int off = 32; off > 0; off >>= 1)
        v += __shfl_down(v, off, 64);
    return v;
}

// q_row[n,f] = Wa_b[f] + sum_e tokens[n,L-1,e] * Wa_w[f,e]; one wave per (n,f)
__global__ void k_qrow(const int* __restrict__ tokens, const float* __restrict__ Wa_w,
                       const float* __restrict__ Wa_b, float* __restrict__ q_row) {
    int wid  = blockIdx.x * (blockDim.x >> 6) + (threadIdx.x >> 6);
    int lane = threadIdx.x & 63;
    int n = wid >> 10;
    int f = wid & (ED - 1);
    const int*   xrow = tokens + ((size_t)n * LS + (LS - 1)) * ED;
    const float* wrow = Wa_w + (size_t)f * ED;
    float acc = 0.f;
    #pragma unroll
    for (int k = 0; k < ED; k += 256) {
        int idx = k + lane * 4;
        int4   t = *reinterpret_cast<const int4*>(xrow + idx);
        float4 w = *reinterpret_cast<const float4*>(wrow + idx);
        acc += (float)t.x * w.x + (float)t.y * w.y + (float)t.z * w.z + (float)t.w * w.w;
    }
    acc = wave_reduce_sum(acc);
    if (lane == 0) q_row[wid] = acc + Wa_b[f];
}

// Flash-style fused kernel: one block (1024 thr) per (n, chunk of 64 m).
// Phase 1: 16 waves compute 4 scores each, packing token bits into LDS.
// Phase 2: chunk softmax (mu_c, z_c, p_m = exp(s_m - mu_c)).
// Phase 3: pa[n,c,e] = sum_m p_m * t[m,e] from packed LDS bits.
__global__ __launch_bounds__(1024) void k_flash(const int* __restrict__ tokens,
                                                const float* __restrict__ q_row,
                                                float* __restrict__ pa,
                                                float* __restrict__ mu_g,
                                                float* __restrict__ z_g) {
    int n = blockIdx.x >> 5;     // /CH
    int c = blockIdx.x & (CH - 1);
    int t = threadIdx.x;
    int wave = t >> 6, lane = t & 63;

    __shared__ unsigned long long pk[CM][16];  // packed token bits, 8 KB
    __shared__ float s_lds[CM];
    __shared__ float p_lds[CM];
    __shared__ float red[4][ED];               // 16 KB partial reduce

    const float* q = q_row + n * ED;

    // ---- phase 1: scores + bit-pack ----
    #pragma unroll
    for (int i = 0; i < 4; ++i) {
        int m = wave + 16 * i;
        const int* row = tokens + ((size_t)(n * LS + c * CM + m)) * ED;
        float acc = 0.f;
        #pragma unroll
        for (int k = 0; k < ED; k += 256) {
            int idx = k + lane * 4;
            int4   tv = *reinterpret_cast<const int4*>(row + idx);
            float4 qv = *reinterpret_cast<const float4*>(q + idx);
            unsigned long long b0 = __ballot(tv.x != 0);
            unsigned long long b1 = __ballot(tv.y != 0);
            unsigned long long b2 = __ballot(tv.z != 0);
            unsigned long long b3 = __ballot(tv.w != 0);
            if (lane == 0) {
                int wb = (k >> 8) * 4;      // element e=k+4l+b -> word (e>>8)*4+b, bit l
                pk[m][wb + 0] = b0; pk[m][wb + 1] = b1;
                pk[m][wb + 2] = b2; pk[m][wb + 3] = b3;
            }
            acc += (float)tv.x * qv.x + (float)tv.y * qv.y
                 + (float)tv.z * qv.z + (float)tv.w * qv.w;
        }
        acc = wave_reduce_sum(acc);
        if (lane == 0) s_lds[m] = acc;
    }
    __syncthreads();

    // ---- phase 2: chunk-local softmax stats (wave 0; CM==64 lanes) ----
    if (wave == 0) {
        float s = s_lds[lane];
        float mx = s;
        #pragma unroll
        for (int off = 32; off > 0; off >>= 1) mx = fmaxf(mx, __shfl_xor(mx, off, 64));
        float p = expf(s - mx);
        float zz = p;
        #pragma unroll
        for (int off = 32; off > 0; off >>= 1) zz += __shfl_xor(zz, off, 64);
        p_lds[lane] = p;
        if (lane == 0) { mu_g[n * CH + c] = mx; z_g[n * CH + c] = zz; }
    }
    __syncthreads();

    // ---- phase 3: weighted bit-sum from LDS ----
    int mg  = t >> 8;          // m residue group 0..3
    int e4  = t & 255;         // e block of 4: e = e4*4 + b
    int wb  = (e4 >> 6) * 4;   // same for all 64 lanes of a wave -> broadcast
    int bit = e4 & 63;
    float a0 = 0.f, a1 = 0.f, a2 = 0.f, a3 = 0.f;
    #pragma unroll
    for (int j = 0; j < 16; ++j) {
        int m = mg + 4 * j;
        float p = p_lds[m];
        unsigned long long w0 = pk[m][wb + 0];
        unsigned long long w1 = pk[m][wb + 1];
        unsigned long long w2 = pk[m][wb + 2];
        unsigned long long w3 = pk[m][wb + 3];
        a0 += ((w0 >> bit) & 1ull) ? p : 0.f;
        a1 += ((w1 >> bit) & 1ull) ? p : 0.f;
        a2 += ((w2 >> bit) & 1ull) ? p : 0.f;
        a3 += ((w3 >> bit) & 1ull) ? p : 0.f;
    }
    *reinterpret_cast<float4*>(&red[mg][e4 * 4]) = make_float4(a0, a1, a2, a3);
    __syncthreads();

    float s4 = red[0][t] + red[1][t] + red[2][t] + red[3][t];  // t == e here
    pa[((size_t)(n * CH + c)) * ED + t] = s4;
}

// Combine chunks: a_row[n,e] = (1/Z) sum_c exp(mu_c - mu) * pa[n,c,e]
__global__ __launch_bounds__(1024) void k_combine(const float* __restrict__ pa,
                                                  const float* __restrict__ mu_g,
                                                  const float* __restrict__ z_g,
                                                  float* __restrict__ a_row) {
    int n = blockIdx.x;
    int t = threadIdx.x;
    __shared__ float coef[CH];
    __shared__ float invZ_s;
    if (t < 64) {
        float m_c = (t < CH) ? mu_g[n * CH + t] : -3.0e38f;
        float mx = m_c;
        #pragma unroll
        for (int off = 32; off > 0; off >>= 1) mx = fmaxf(mx, __shfl_xor(mx, off, 64));
        float cf = (t < CH) ? expf(m_c - mx) : 0.f;
        float zc = (t < CH) ? z_g[n * CH + t] * cf : 0.f;
        float Z = zc;
        #pragma unroll
        for (int off = 32; off > 0; off >>= 1) Z += __shfl_xor(Z, off, 64);
        if (t < CH) coef[t] = cf;
        if (t == 0) invZ_s = 1.f / Z;
    }
    __syncthreads();
    float inv = invZ_s;
    float acc = 0.f;
    #pragma unroll
    for (int ci = 0; ci < CH; ++ci)
        acc += coef[ci] * pa[((size_t)(n * CH + ci)) * ED + t];
    a_row[n * ED + t] = acc * inv;
}

// out[n,v] = Wb_b[v] + sum_e a_row[n,e] * Wb_w[v,e]; one wave per (n,v)
__global__ void k_out(const float* __restrict__ a_row, const float* __restrict__ Wb_w,
                      const float* __restrict__ Wb_b, float* __restrict__ out) {
    int wid  = blockIdx.x * (blockDim.x >> 6) + (threadIdx.x >> 6);
    int lane = threadIdx.x & 63;
    int n = wid >> 9;
    int v = wid & (VD - 1);
    const float* a  = a_row + n * ED;
    const float* wr = Wb_w + (size_t)v * ED;
    float acc = 0.f;
    #pragma unroll
    for (int k = 0; k < ED; k += 256) {
        int idx = k + lane * 4;
        float4 av = *reinterpret_cast<const float4*>(a + idx);
        float4 wv = *reinterpret_cast<const float4*>(wr + idx);
        acc += av.x * wv.x + av.y * wv.y + av.z * wv.z + av.w * wv.w;
    }
    acc = wave_reduce_sum(acc);
    if (lane == 0) out[wid] = acc + Wb_b[v];
}

extern "C" void kernel_launch(void* const* d_in, const int* in_sizes, int n_in,
                              void* d_out, int out_size, void* d_ws, size_t ws_size,
                              hipStream_t stream) {
    const int*   tokens = (const int*)  d_in[0];
    const float* Wa_w   = (const float*)d_in[1];
    const float* Wa_b   = (const float*)d_in[2];
    const float* Wb_w   = (const float*)d_in[3];
    const float* Wb_b   = (const float*)d_in[4];
    float* out = (float*)d_out;

    float* ws    = (float*)d_ws;
    float* q_row = ws;                               // 8192
    float* pa    = q_row + NB * ED;                  // 8*32*1024 = 262144
    float* mu_g  = pa + (size_t)NB * CH * ED;        // 256
    float* z_g   = mu_g + NB * CH;                   // 256
    float* a_row = z_g + NB * CH;                    // 8192

    // 1) q_row: 8192 waves -> 2048 blocks of 256
    k_qrow<<<dim3((NB * ED) / 4), dim3(256), 0, stream>>>(tokens, Wa_w, Wa_b, q_row);
    // 2) fused scores+softmax+weighted-sum: 256 blocks of 1024 (reads tokens ONCE)
    k_flash<<<dim3(NB * CH), dim3(1024), 0, stream>>>(tokens, q_row, pa, mu_g, z_g);
    // 3) combine chunk partials: 8 blocks of 1024
    k_combine<<<dim3(NB), dim3(1024), 0, stream>>>(pa, mu_g, z_g, a_row);
    // 4) final GEMV: 4096 waves -> 1024 blocks of 256
    k_out<<<dim3((NB * VD) / 4), dim3(256), 0, stream>>>(a_row, Wb_w, Wb_b, out);
}